// Round 5
// baseline (681.752 us; speedup 1.0000x reference)
//
#include <hip/hip_runtime.h>
#include <stdint.h>

// Problem constants (match reference)
#define NUM_STEPS  256
#define INPUT_SIZE 784
#define N_NEURONS  512

typedef float    v4f __attribute__((ext_vector_type(4)));
typedef uint16_t v4h __attribute__((ext_vector_type(4)));

// bf16 <-> fp32 helpers (bit-exact widen; RNE narrow)
__device__ __forceinline__ float bf2f(unsigned short u) {
    union { uint32_t i; float f; } v; v.i = ((uint32_t)u) << 16; return v.f;
}
__device__ __forceinline__ unsigned short f2bf(float f) {
    union { float f; uint32_t i; } v; v.f = f;
    uint32_t x = v.i;
    return (unsigned short)((x + 0x7fffu + ((x >> 16) & 1u)) >> 16);
}

template <bool F32>
__device__ __forceinline__ void ld_chunk(const void* __restrict__ base, size_t elem, float* d) {
    if constexpr (F32) {
        const v4f v = *(const v4f*)((const float*)base + elem);
        d[0] = v.x; d[1] = v.y; d[2] = v.z; d[3] = v.w;
    } else {
        const v4h v = *(const v4h*)((const unsigned short*)base + elem);
        d[0] = bf2f(v.x); d[1] = bf2f(v.y); d[2] = bf2f(v.z); d[3] = bf2f(v.w);
    }
}

// Non-temporal store of one 4-element chunk (write-once 411MB stream: skip L2).
template <bool F32>
__device__ __forceinline__ void st_chunk_nt(void* __restrict__ base, size_t elem, const float* s) {
    if constexpr (F32) {
        v4f v; v.x = s[0]; v.y = s[1]; v.z = s[2]; v.w = s[3];
        __builtin_nontemporal_store(v, (v4f*)((float*)base + elem));
    } else {
        v4h v; v.x = f2bf(s[0]); v.y = f2bf(s[1]); v.z = f2bf(s[2]); v.w = f2bf(s[3]);
        __builtin_nontemporal_store(v, (v4h*)((unsigned short*)base + elem));
    }
}

__device__ __forceinline__ bool sniff_f32(const void* W) {
    // bf16 data in [0,1] never has a 16-bit halfword > 0x3F80; fp32 low
    // halfwords are random mantissa bits. Uniform across all threads.
    const unsigned short* w16 = (const unsigned short*)W;
    bool f32 = false;
    for (int i = 0; i < 128; ++i) f32 |= (w16[i] > 0x3F80u);
    return f32;
}

// ============================ PHASE 1 ======================================
// One wave per neuron row, 2 rows/block. Full serial scan; NO W_rec stores
// (the weight evolution is recomputed in phase 2 from the spk/post trains).
// Emits spk/mem/syn/post to d_out (staged in LDS, dumped per 64 steps) and an
// fp32 post side-channel to d_ws (bit-consistency for the bf16 path).
template <bool F32>
__device__ void scan_run(const void* __restrict__ img_v,
                         const void* __restrict__ W_v,
                         void* __restrict__ out_v,
                         float* __restrict__ ws_post,
                         uint2 (&msk)[64][64],
                         float (&sbuf)[2][64][4])
{
    const int tid  = threadIdx.x;
    const int wid  = tid >> 6;
    const int lane = tid & 63;
    const int row  = (blockIdx.x << 1) | wid;
    const bool has4 = lane < 4;

    const size_t WREC = (size_t)NUM_STEPS * N_NEURONS * INPUT_SIZE;
    const size_t SREC = (size_t)NUM_STEPS * N_NEURONS;

    size_t cofs[4];
    cofs[0] = (size_t)(lane      ) * 4;
    cofs[1] = (size_t)(lane +  64) * 4;
    cofs[2] = (size_t)(lane + 128) * 4;
    cofs[3] = (size_t)(192 + lane) * 4;   // lanes 0..3 only

    // ---- pre-pass: pack image spike bits into LDS (split across 2 waves) ----
    for (int i = wid; i < 64; i += 2) {          // i indexes groups of 4 steps
        uint32_t lo = 0, hi = 0;
        #pragma unroll
        for (int s = 0; s < 4; ++s) {
            const int t = 4 * i + s;
            float a[4][4] = {};
            const size_t xb = (size_t)t * INPUT_SIZE;
            ld_chunk<F32>(img_v, xb + cofs[0], a[0]);
            ld_chunk<F32>(img_v, xb + cofs[1], a[1]);
            ld_chunk<F32>(img_v, xb + cofs[2], a[2]);
            if (has4) ld_chunk<F32>(img_v, xb + cofs[3], a[3]);
            uint32_t m = 0;
            #pragma unroll
            for (int c = 0; c < 4; ++c)
                #pragma unroll
                for (int j = 0; j < 4; ++j)
                    m |= (uint32_t)(a[c][j] != 0.0f) << (4 * c + j);
            if      (s == 0) lo  = m;
            else if (s == 1) lo |= m << 16;
            else if (s == 2) hi  = m;
            else             hi |= m << 16;
        }
        msk[i][lane] = make_uint2(lo, hi);
    }

    // ---- weight row + pre-trace in registers ----
    float w[16], p[16];
    #pragma unroll
    for (int k = 0; k < 16; ++k) { w[k] = 0.f; p[k] = 0.f; }
    {
        const size_t wbase = (size_t)row * INPUT_SIZE;
        ld_chunk<F32>(W_v, wbase + cofs[0], &w[0]);
        ld_chunk<F32>(W_v, wbase + cofs[1], &w[4]);
        ld_chunk<F32>(W_v, wbase + cofs[2], &w[8]);
        if (has4) ld_chunk<F32>(W_v, wbase + cofs[3], &w[12]);
    }

    __syncthreads();   // masks visible across the 2 waves (uniform branch above)

    float syn = 0.f, mem = 0.f, spk_prev = 0.f, post = 0.f;
    int t = 0;

#define STEP(MB) do {                                                           \
        const uint32_t mb_ = (MB);                                              \
        float xf[16];                                                           \
        _Pragma("unroll")                                                       \
        for (int k = 0; k < 16; ++k) xf[k] = ((mb_ >> k) & 1u) ? 1.0f : 0.0f;   \
        float g[8];                                                             \
        _Pragma("unroll")                                                       \
        for (int k = 0; k < 8; ++k)                                             \
            g[k] = w[2*k] * xf[2*k] + w[2*k+1] * xf[2*k+1];                     \
        const float h0_ = (g[0] + g[1]) + (g[2] + g[3]);                        \
        const float h1_ = (g[4] + g[5]) + (g[6] + g[7]);                        \
        float partial = h0_ + h1_;                                              \
        _Pragma("unroll")                                                       \
        for (int off = 1; off < 64; off <<= 1)                                  \
            partial += __shfl_xor(partial, off, 64);                            \
        syn = 0.9f * syn + partial;                                             \
        mem = 0.8f * mem + syn - spk_prev;                                      \
        const float spk = (mem > 1.0f) ? 1.0f : 0.0f;                           \
        post = 0.9f * post + spk;                                               \
        const float ap = 0.008f * spk, am = 0.0066f * post;                     \
        _Pragma("unroll")                                                       \
        for (int k = 0; k < 16; ++k)                                            \
            w[k] = fminf(fmaxf(w[k] + ap * p[k] - am * xf[k], 0.0f), 1.0f);     \
        if (lane == 0) {                                                        \
            v4f sv_; sv_.x = spk; sv_.y = mem; sv_.z = syn; sv_.w = post;       \
            *(v4f*)&sbuf[wid][t & 63][0] = sv_;                                 \
        }                                                                       \
        _Pragma("unroll")                                                       \
        for (int k = 0; k < 16; ++k) p[k] = 0.9f * p[k] + xf[k];                \
        spk_prev = spk; ++t;                                                    \
    } while (0)

    for (int i = 0; i < 64; ++i) {
        const uint2 mp = msk[i][lane];       // ds_read_b64, lgkm only
        STEP(mp.x & 0xFFFFu);
        STEP(mp.x >> 16);
        STEP(mp.y & 0xFFFFu);
        STEP(mp.y >> 16);
        if ((i & 15) == 15) {                // dump 64 steps of scalar state
            const int t0 = (i - 15) * 4;
            const v4f sv = *(const v4f*)&sbuf[wid][lane][0];
            const size_t rr = (size_t)(t0 + lane) * N_NEURONS + row;
            if constexpr (F32) {
                float* out = (float*)out_v;
                out[WREC + 0 * SREC + rr] = sv.x;
                out[WREC + 1 * SREC + rr] = sv.y;
                out[WREC + 2 * SREC + rr] = sv.z;
                out[WREC + 3 * SREC + rr] = sv.w;
            } else {
                unsigned short* out = (unsigned short*)out_v;
                out[WREC + 0 * SREC + rr] = f2bf(sv.x);
                out[WREC + 1 * SREC + rr] = f2bf(sv.y);
                out[WREC + 2 * SREC + rr] = f2bf(sv.z);
                out[WREC + 3 * SREC + rr] = f2bf(sv.w);
            }
            if (ws_post) ws_post[rr] = sv.w;   // exact fp32 post side-channel
        }
    }
#undef STEP
}

__global__ __launch_bounds__(128) void snn_phase1_kernel(
    const void* __restrict__ img,
    const void* __restrict__ W,
    void* __restrict__ out,
    float* __restrict__ ws_post)
{
    __shared__ uint2 msk[64][64];      // 32 KB
    __shared__ float sbuf[2][64][4];   // 2 KB
    if (sniff_f32(W)) scan_run<true >(img, W, out, ws_post, msk, sbuf);
    else              scan_run<false>(img, W, out, ws_post, msk, sbuf);
}

// ============================ PHASE 2 ======================================
// Given spk/post trains (stream-ordered after phase 1), the per-column weight
// scan is independent across columns: 512 rows x 4 column-quarters = 2048
// single-wave blocks (8/CU by LDS). Pre-pass packs x-bits + ap/am into LDS;
// main loop is pure VALU + one NT store per active lane per step -> the store
// pipe is saturated by wave-level parallelism, with no serial chain in sight.
template <bool F32>
__device__ void store_run(const void* __restrict__ img_v,
                          const void* __restrict__ W_v,
                          void* __restrict__ out_v,
                          const float* __restrict__ ws_post,
                          uint8_t (&msk8)[NUM_STEPS][64],
                          float (&apam)[NUM_STEPS][2])
{
    const int lane = threadIdx.x;          // 64 threads = 1 wave (no barriers)
    const int row  = blockIdx.x >> 2;
    const int q    = blockIdx.x & 3;
    const bool act = lane < 49;            // 49 chunks per quarter (4*49=196)
    const int  col = (196 * q + 4 * lane); // column base (aligned: 16B fp32 / 8B bf16)

    const size_t WREC = (size_t)NUM_STEPS * N_NEURONS * INPUT_SIZE;
    const size_t SREC = (size_t)NUM_STEPS * N_NEURONS;

    // ---- pre-pass A: ap/am per step into LDS ----
    for (int k = lane; k < NUM_STEPS; k += 64) {
        const size_t rr = (size_t)k * N_NEURONS + row;
        float spk, post;
        if constexpr (F32) {
            const float* o = (const float*)out_v;
            spk  = o[WREC + 0 * SREC + rr];
            post = o[WREC + 3 * SREC + rr];
        } else {
            const unsigned short* o = (const unsigned short*)out_v;
            spk  = bf2f(o[WREC + 0 * SREC + rr]);
            post = bf2f(o[WREC + 3 * SREC + rr]);
        }
        if (ws_post) post = ws_post[rr];   // exact fp32 (matters for bf16 path)
        apam[k][0] = 0.008f  * spk;
        apam[k][1] = 0.0066f * post;
    }

    // ---- pre-pass B: pack this quarter's x-bits into LDS ----
    if (act) {
        for (int t = 0; t < NUM_STEPS; ++t) {
            float a[4];
            ld_chunk<F32>(img_v, (size_t)t * INPUT_SIZE + col, a);
            uint32_t m = 0;
            #pragma unroll
            for (int j = 0; j < 4; ++j) m |= (uint32_t)(a[j] != 0.0f) << j;
            msk8[t][lane] = (uint8_t)m;
        }
    }
    // single wave: LDS ops retire in-order within the wave, no barrier needed

    float w[4] = {0.f, 0.f, 0.f, 0.f}, p[4] = {0.f, 0.f, 0.f, 0.f};
    if (act) ld_chunk<F32>(W_v, (size_t)row * INPUT_SIZE + col, w);

    #pragma unroll 4
    for (int t = 0; t < NUM_STEPS; ++t) {
        const uint32_t m = msk8[t][lane];
        const float ap = apam[t][0], am = apam[t][1];
        float x[4];
        #pragma unroll
        for (int j = 0; j < 4; ++j) x[j] = ((m >> j) & 1u) ? 1.0f : 0.0f;
        // identical expression tree to phase 1's update (bit-consistency)
        #pragma unroll
        for (int j = 0; j < 4; ++j)
            w[j] = fminf(fmaxf(w[j] + ap * p[j] - am * x[j], 0.0f), 1.0f);
        if (act)
            st_chunk_nt<F32>(out_v, ((size_t)t * N_NEURONS + row) * INPUT_SIZE + col, w);
        #pragma unroll
        for (int j = 0; j < 4; ++j) p[j] = 0.9f * p[j] + x[j];
    }
}

__global__ __launch_bounds__(64) void snn_phase2_kernel(
    const void* __restrict__ img,
    const void* __restrict__ W,
    void* __restrict__ out,
    const float* __restrict__ ws_post)
{
    __shared__ uint8_t msk8[NUM_STEPS][64];   // 16 KB
    __shared__ float   apam[NUM_STEPS][2];    //  2 KB
    if (sniff_f32(W)) store_run<true >(img, W, out, ws_post, msk8, apam);
    else              store_run<false>(img, W, out, ws_post, msk8, apam);
}

extern "C" void kernel_launch(void* const* d_in, const int* in_sizes, int n_in,
                              void* d_out, int out_size, void* d_ws, size_t ws_size,
                              hipStream_t stream) {
    (void)in_sizes; (void)n_in; (void)out_size;
    float* ws_post = (d_ws && ws_size >= (size_t)NUM_STEPS * N_NEURONS * sizeof(float))
                   ? (float*)d_ws : nullptr;
    snn_phase1_kernel<<<dim3(N_NEURONS / 2), dim3(128), 0, stream>>>(d_in[0], d_in[1], d_out, ws_post);
    snn_phase2_kernel<<<dim3(N_NEURONS * 4), dim3(64),  0, stream>>>(d_in[0], d_in[1], d_out, ws_post);
}